// Round 1
// baseline (390.677 us; speedup 1.0000x reference)
//
#include <hip/hip_runtime.h>
#include <hip/hip_fp16.h>

#define OUTPUT_DIM 128
#define INV_KEEP 1.1111112f   // float(1.0/0.9)

// ---------- Kernel 1: convert f32 weights -> f16 into workspace ----------
__global__ void convert_w_kernel(const float* __restrict__ w,
                                 __half* __restrict__ wh, int n) {
    int i = blockIdx.x * blockDim.x + threadIdx.x;
    int i4 = i * 4;
    if (i4 + 3 < n) {
        float4 f = *(const float4*)(w + i4);
        __half2 h0 = __floats2half2_rn(f.x, f.y);
        __half2 h1 = __floats2half2_rn(f.z, f.w);
        *(__half2*)(wh + i4)     = h0;
        *(__half2*)(wh + i4 + 2) = h1;
    } else {
        for (int k = i4; k < n; ++k) wh[k] = __float2half(w[k]);
    }
}

// ---------- helpers to load a 2-wide W fragment as float2 ----------
__device__ __forceinline__ float2 load_w2(const __half* __restrict__ wh, size_t off) {
    __half2 h = *(const __half2*)(wh + off);
    return __half22float2(h);
}
__device__ __forceinline__ float2 load_w2(const float* __restrict__ wf, size_t off) {
    return *(const float2*)(wf + off);
}

// ---------- Kernel 2: segmented SpMM ----------
// One wave (64 threads) per segment of R rows. Lane owns output columns
// (2*lane, 2*lane+1). rows[] is sorted ascending, so each segment's nnz
// form one contiguous range found by binary search. No atomics: every
// output row is written exactly once (bias-only for empty rows).
template <typename WT, int R>
__global__ void __launch_bounds__(64)
spmm_kernel(const float* __restrict__ vals,
            const int*   __restrict__ rows,
            const int*   __restrict__ cols,
            const int*   __restrict__ mask,
            const WT*    __restrict__ wmat,
            const float* __restrict__ bias,
            float*       __restrict__ out,
            int nnz, int n_nodes) {
    const int seg  = blockIdx.x;
    const int r0   = seg * R;
    const int r1   = min(r0 + R, n_nodes);
    const int lane = threadIdx.x;          // 0..63
    const int cofs = 2 * lane;             // column offset this lane owns

    // lower_bound on sorted rows[]
    auto lb = [&](int target) {
        int lo = 0, hi = nnz;
        while (lo < hi) {
            int mid = (lo + hi) >> 1;
            if (rows[mid] < target) lo = mid + 1; else hi = mid;
        }
        return lo;
    };
    int i0 = __builtin_amdgcn_readfirstlane(lb(r0));
    int i1 = __builtin_amdgcn_readfirstlane(lb(r1));

    const float2 b = ((const float2*)bias)[lane];
    float2 acc = b;
    int cur = r0;

    #pragma unroll 4
    for (int i = i0; i < i1; ++i) {
        int r = rows[i];
        if (r != cur) {
            // flush finished row, bias-fill any empty rows in between
            *(float2*)(out + (size_t)cur * OUTPUT_DIM + cofs) = acc;
            for (int rr = cur + 1; rr < r; ++rr)
                *(float2*)(out + (size_t)rr * OUTPUT_DIM + cofs) = b;
            cur = r;
            acc = b;
        }
        int   m = mask[i];
        float v = m ? vals[i] * INV_KEEP : 0.0f;
        float2 w = load_w2(wmat, (size_t)cols[i] * OUTPUT_DIM + cofs);
        acc.x = fmaf(v, w.x, acc.x);
        acc.y = fmaf(v, w.y, acc.y);
    }
    // flush last open row + bias-fill trailing empty rows of the segment
    *(float2*)(out + (size_t)cur * OUTPUT_DIM + cofs) = acc;
    for (int rr = cur + 1; rr < r1; ++rr)
        *(float2*)(out + (size_t)rr * OUTPUT_DIM + cofs) = b;
}

extern "C" void kernel_launch(void* const* d_in, const int* in_sizes, int n_in,
                              void* d_out, int out_size, void* d_ws, size_t ws_size,
                              hipStream_t stream) {
    const float* vals = (const float*)d_in[0];
    const int*   rows = (const int*)  d_in[1];
    const int*   cols = (const int*)  d_in[2];
    const int*   mask = (const int*)  d_in[3];
    const float* W    = (const float*)d_in[4];
    const float* bias = (const float*)d_in[5];
    float*       out  = (float*)d_out;

    const int nnz      = in_sizes[0];
    const int w_elems  = in_sizes[4];               // INPUT_DIM * OUTPUT_DIM
    const int n_nodes  = out_size / OUTPUT_DIM;

    constexpr int R = 16;                            // rows per segment/wave
    const int segs = (n_nodes + R - 1) / R;

    const size_t wh_bytes = (size_t)w_elems * sizeof(__half);
    if (ws_size >= wh_bytes) {
        __half* wh = (__half*)d_ws;
        int cvt_threads = (w_elems + 3) / 4;
        convert_w_kernel<<<(cvt_threads + 255) / 256, 256, 0, stream>>>(W, wh, w_elems);
        spmm_kernel<__half, R><<<segs, 64, 0, stream>>>(
            vals, rows, cols, mask, wh, bias, out, nnz, n_nodes);
    } else {
        spmm_kernel<float, R><<<segs, 64, 0, stream>>>(
            vals, rows, cols, mask, W, bias, out, nnz, n_nodes);
    }
}

// Round 2
// 229.244 us; speedup vs baseline: 1.7042x; 1.7042x over previous
//
#include <hip/hip_runtime.h>
#include <hip/hip_fp16.h>

#define ODIM 128
#define INV_KEEP 1.1111112f   // float(1.0/0.9)
#define SEG_SHIFT 4           // 16 rows per segment
#define SEG_R (1 << SEG_SHIFT)

// ---------- Kernel: convert f32 weights -> f16 into workspace ----------
__global__ void convert_w_kernel(const float* __restrict__ w,
                                 __half* __restrict__ wh, int n) {
    int i = blockIdx.x * blockDim.x + threadIdx.x;
    int i4 = i * 4;
    if (i4 + 3 < n) {
        float4 f = *(const float4*)(w + i4);
        *(__half2*)(wh + i4)     = __floats2half2_rn(f.x, f.y);
        *(__half2*)(wh + i4 + 2) = __floats2half2_rn(f.z, f.w);
    } else {
        for (int k = i4; k < n; ++k) wh[k] = __float2half(w[k]);
    }
}

// ---------- Kernels: build segment pointers from sorted rows ----------
__global__ void segptr_init_kernel(int* __restrict__ seg_ptr, int n, int nnz) {
    int i = blockIdx.x * blockDim.x + threadIdx.x;
    if (i < n) seg_ptr[i] = nnz;
}

__global__ void segptr_scatter_kernel(const int* __restrict__ rows,
                                      int* __restrict__ seg_ptr, int nnz) {
    int i = blockIdx.x * blockDim.x + threadIdx.x;
    if (i >= nnz) return;
    int s_cur  = rows[i] >> SEG_SHIFT;
    int s_prev = (i == 0) ? -1 : (rows[i - 1] >> SEG_SHIFT);
    // i is the first nnz at-or-after every segment in (s_prev, s_cur]
    for (int s = s_prev + 1; s <= s_cur; ++s) seg_ptr[s] = i;
}

// ---------- helpers: load a 2-wide W fragment as float2 ----------
__device__ __forceinline__ float2 load_w2(const __half* __restrict__ wh, int off) {
    __half2 h = *(const __half2*)(wh + off);
    return __half22float2(h);
}
__device__ __forceinline__ float2 load_w2(const float* __restrict__ wf, int off) {
    return *(const float2*)(wf + off);
}

// ---------- Main SpMM: one wave per 16-row segment ----------
// Lane owns output columns (2*lane, 2*lane+1). nnz processed in batches of
// 64: lanes cooperatively load 64 nnz (coalesced), then broadcast each via
// __shfl. W loads staged 8-deep for memory-level parallelism. No atomics.
template <typename WT>
__global__ void __launch_bounds__(256, 8)
spmm_kernel(const float* __restrict__ vals,
            const int*   __restrict__ rows,
            const int*   __restrict__ cols,
            const int*   __restrict__ mask,
            const WT*    __restrict__ wmat,
            const float* __restrict__ bias,
            const int*   __restrict__ seg_ptr,   // may be null -> binary search
            float*       __restrict__ out,
            int nnz, int n_nodes) {
    const int wave = threadIdx.x >> 6;
    const int lane = threadIdx.x & 63;
    const int seg  = blockIdx.x * 4 + wave;
    const int nsegs = (n_nodes + SEG_R - 1) >> SEG_SHIFT;
    if (seg >= nsegs) return;
    const int r0 = seg << SEG_SHIFT;
    const int r1 = min(r0 + SEG_R, n_nodes);
    const int cofs = 2 * lane;

    int i0, i1;
    if (seg_ptr) {
        i0 = seg_ptr[seg];
        i1 = seg_ptr[seg + 1];
    } else {
        auto lb = [&](int target) {
            int lo = 0, hi = nnz;
            while (lo < hi) {
                int mid = (lo + hi) >> 1;
                if (rows[mid] < target) lo = mid + 1; else hi = mid;
            }
            return lo;
        };
        i0 = __builtin_amdgcn_readfirstlane(lb(r0));
        i1 = __builtin_amdgcn_readfirstlane(lb(r1));
    }

    const float2 b = ((const float2*)bias)[lane];
    float2 acc = b;
    int cur = r0;

    for (int base = i0; base < i1; base += 64) {
        const int n = min(64, i1 - base);
        const int idx = base + lane;
        int r = 0, c = 0;
        float v = 0.0f;
        if (lane < n) {
            r = rows[idx];
            c = cols[idx];
            int m = mask[idx];
            v = m ? vals[idx] * INV_KEEP : 0.0f;
        }
        for (int j0 = 0; j0 < n; j0 += 8) {
            const int cnt = min(8, n - j0);
            float2 w[8];
            // stage 8 independent, coalesced W loads
            #pragma unroll
            for (int k = 0; k < 8; ++k) {
                if (k < cnt) {
                    int cj = __shfl(c, j0 + k);
                    w[k] = load_w2(wmat, cj * ODIM + cofs);
                }
            }
            // consume
            #pragma unroll
            for (int k = 0; k < 8; ++k) {
                if (k < cnt) {
                    int   rj = __shfl(r, j0 + k);
                    float vj = __shfl(v, j0 + k);
                    if (rj != cur) {
                        *(float2*)(out + (size_t)cur * ODIM + cofs) = acc;
                        for (int rr = cur + 1; rr < rj; ++rr)
                            *(float2*)(out + (size_t)rr * ODIM + cofs) = b;
                        cur = rj;
                        acc = b;
                    }
                    acc.x = fmaf(vj, w[k].x, acc.x);
                    acc.y = fmaf(vj, w[k].y, acc.y);
                }
            }
        }
    }
    *(float2*)(out + (size_t)cur * ODIM + cofs) = acc;
    for (int rr = cur + 1; rr < r1; ++rr)
        *(float2*)(out + (size_t)rr * ODIM + cofs) = b;
}

extern "C" void kernel_launch(void* const* d_in, const int* in_sizes, int n_in,
                              void* d_out, int out_size, void* d_ws, size_t ws_size,
                              hipStream_t stream) {
    const float* vals = (const float*)d_in[0];
    const int*   rows = (const int*)  d_in[1];
    const int*   cols = (const int*)  d_in[2];
    const int*   mask = (const int*)  d_in[3];
    const float* W    = (const float*)d_in[4];
    const float* bias = (const float*)d_in[5];
    float*       out  = (float*)d_out;

    const int nnz     = in_sizes[0];
    const int w_elems = in_sizes[4];             // INPUT_DIM * OUTPUT_DIM
    const int n_nodes = out_size / ODIM;
    const int nsegs   = (n_nodes + SEG_R - 1) >> SEG_SHIFT;

    // workspace layout: [W as f16 | seg_ptr]
    const size_t wh_bytes = ((size_t)w_elems * sizeof(__half) + 255) & ~(size_t)255;
    const size_t sp_bytes = (size_t)(nsegs + 1) * sizeof(int);

    __half* wh = nullptr;
    int* seg_ptr = nullptr;
    if (ws_size >= wh_bytes + sp_bytes) {
        wh = (__half*)d_ws;
        seg_ptr = (int*)((char*)d_ws + wh_bytes);
    } else if (ws_size >= sp_bytes) {
        seg_ptr = (int*)d_ws;
    }

    if (seg_ptr) {
        segptr_init_kernel<<<(nsegs + 1 + 255) / 256, 256, 0, stream>>>(seg_ptr, nsegs + 1, nnz);
        segptr_scatter_kernel<<<(nnz + 255) / 256, 256, 0, stream>>>(rows, seg_ptr, nnz);
    }

    const int blocks = (nsegs + 3) / 4;   // 4 waves (segments) per 256-thread block
    if (wh) {
        int cvt_threads = (w_elems + 3) / 4;
        convert_w_kernel<<<(cvt_threads + 255) / 256, 256, 0, stream>>>(W, wh, w_elems);
        spmm_kernel<__half><<<blocks, 256, 0, stream>>>(
            vals, rows, cols, mask, wh, bias, seg_ptr, out, nnz, n_nodes);
    } else {
        spmm_kernel<float><<<blocks, 256, 0, stream>>>(
            vals, rows, cols, mask, W, bias, seg_ptr, out, nnz, n_nodes);
    }
}

// Round 3
// 179.006 us; speedup vs baseline: 2.1825x; 1.2806x over previous
//
#include <hip/hip_runtime.h>
#include <hip/hip_fp16.h>

#define ODIM 128
#define INV_KEEP 1.1111112f   // float(1.0/0.9)

// ---------- Fused prep kernel ----------
// Blocks [0, cvt_blocks): convert f32 W -> f16 into workspace (4 elems/thread).
// Blocks [cvt_blocks, ...): build CSR row_ptr from sorted rows[] by scatter:
//   row_ptr[r] = first i with rows[i] >= r.
__global__ void prep_kernel(const float* __restrict__ w, __half* __restrict__ wh,
                            int w_elems,
                            const int* __restrict__ rows, int* __restrict__ row_ptr,
                            int nnz, int n_nodes, int cvt_blocks) {
    if ((int)blockIdx.x < cvt_blocks) {
        int i4 = (blockIdx.x * 256 + threadIdx.x) * 4;
        if (i4 + 3 < w_elems) {
            float4 f = *(const float4*)(w + i4);
            *(__half2*)(wh + i4)     = __floats2half2_rn(f.x, f.y);
            *(__half2*)(wh + i4 + 2) = __floats2half2_rn(f.z, f.w);
        } else {
            for (int k = i4; k < w_elems; ++k) wh[k] = __float2half(w[k]);
        }
    } else {
        int i = (blockIdx.x - cvt_blocks) * 256 + threadIdx.x;
        if (i >= nnz) return;
        int r_cur  = rows[i];
        int r_prev = (i == 0) ? -1 : rows[i - 1];
        for (int r = r_prev + 1; r <= r_cur; ++r) row_ptr[r] = i;
        if (i == nnz - 1)
            for (int r = r_cur + 1; r <= n_nodes; ++r) row_ptr[r] = nnz;
    }
}

// ---------- helpers: load a 2-wide W fragment as float2 ----------
__device__ __forceinline__ float2 load_w2(const __half* __restrict__ wh, int off) {
    __half2 h = *(const __half2*)(wh + off);
    return __half22float2(h);
}
__device__ __forceinline__ float2 load_w2(const float* __restrict__ wf, int off) {
    return *(const float2*)(wf + off);
}

// ---------- Main SpMM: one wave per output row ----------
// Lane owns output columns (2*lane, 2*lane+1). Per-nnz scalars are uniform
// broadcast loads (SGPR loop bounds via readfirstlane); W gathers are
// wave-coalesced 256B loads, 8 independent in flight per batch. No branches
// inside the unrolled body, no shfl, no atomics.
template <typename WT>
__global__ void __launch_bounds__(256, 8)
spmm_kernel(const float* __restrict__ vals,
            const int*   __restrict__ rows,
            const int*   __restrict__ cols,
            const int*   __restrict__ mask,
            const WT*    __restrict__ wmat,
            const float* __restrict__ bias,
            const int*   __restrict__ row_ptr,   // may be null -> binary search
            float*       __restrict__ out,
            int nnz, int n_nodes) {
    const int wave = threadIdx.x >> 6;
    const int lane = threadIdx.x & 63;
    const int row  = blockIdx.x * 4 + wave;
    if (row >= n_nodes) return;
    const int cofs = 2 * lane;

    int i0, i1;
    if (row_ptr) {
        i0 = __builtin_amdgcn_readfirstlane(row_ptr[row]);
        i1 = __builtin_amdgcn_readfirstlane(row_ptr[row + 1]);
    } else {
        auto lb = [&](int target) {
            int lo = 0, hi = nnz;
            while (lo < hi) {
                int mid = (lo + hi) >> 1;
                if (rows[mid] < target) lo = mid + 1; else hi = mid;
            }
            return lo;
        };
        i0 = __builtin_amdgcn_readfirstlane(lb(row));
        i1 = __builtin_amdgcn_readfirstlane(lb(row + 1));
    }

    float2 acc = ((const float2*)bias)[lane];

    int i = i0;
    for (; i + 8 <= i1; i += 8) {
        int c[8];
        float v[8];
        float2 w[8];
        #pragma unroll
        for (int k = 0; k < 8; ++k) c[k] = cols[i + k];
        #pragma unroll
        for (int k = 0; k < 8; ++k) {
            float val = vals[i + k];
            v[k] = mask[i + k] ? val * INV_KEEP : 0.0f;
        }
        #pragma unroll
        for (int k = 0; k < 8; ++k) w[k] = load_w2(wmat, c[k] * ODIM + cofs);
        #pragma unroll
        for (int k = 0; k < 8; ++k) {
            acc.x = fmaf(v[k], w[k].x, acc.x);
            acc.y = fmaf(v[k], w[k].y, acc.y);
        }
    }
    // remainder (<8 nnz), independent iterations
    #pragma unroll 1
    for (; i < i1; ++i) {
        int c = cols[i];
        float v = mask[i] ? vals[i] * INV_KEEP : 0.0f;
        float2 w = load_w2(wmat, c * ODIM + cofs);
        acc.x = fmaf(v, w.x, acc.x);
        acc.y = fmaf(v, w.y, acc.y);
    }

    *(float2*)(out + (size_t)row * ODIM + cofs) = acc;
}

extern "C" void kernel_launch(void* const* d_in, const int* in_sizes, int n_in,
                              void* d_out, int out_size, void* d_ws, size_t ws_size,
                              hipStream_t stream) {
    const float* vals = (const float*)d_in[0];
    const int*   rows = (const int*)  d_in[1];
    const int*   cols = (const int*)  d_in[2];
    const int*   mask = (const int*)  d_in[3];
    const float* W    = (const float*)d_in[4];
    const float* bias = (const float*)d_in[5];
    float*       out  = (float*)d_out;

    const int nnz     = in_sizes[0];
    const int w_elems = in_sizes[4];             // INPUT_DIM * OUTPUT_DIM
    const int n_nodes = out_size / ODIM;

    // workspace layout: [W as f16 (256B aligned) | row_ptr (n_nodes+1 ints)]
    const size_t wh_bytes = ((size_t)w_elems * sizeof(__half) + 255) & ~(size_t)255;
    const size_t rp_bytes = (size_t)(n_nodes + 1) * sizeof(int);

    __half* wh = nullptr;
    int* row_ptr = nullptr;
    if (ws_size >= wh_bytes + rp_bytes) {
        wh = (__half*)d_ws;
        row_ptr = (int*)((char*)d_ws + wh_bytes);
    } else if (ws_size >= rp_bytes) {
        row_ptr = (int*)d_ws;
    }

    const int cvt_blocks = wh ? (w_elems / 4 + 255) / 256 : 0;
    const int rp_blocks  = row_ptr ? (nnz + 255) / 256 : 0;
    if (cvt_blocks + rp_blocks > 0)
        prep_kernel<<<cvt_blocks + rp_blocks, 256, 0, stream>>>(
            W, wh, w_elems, rows, row_ptr, nnz, n_nodes, cvt_blocks);

    const int blocks = (n_nodes + 3) / 4;   // 4 rows (waves) per 256-thread block
    if (wh) {
        spmm_kernel<__half><<<blocks, 256, 0, stream>>>(
            vals, rows, cols, mask, wh, bias, row_ptr, out, nnz, n_nodes);
    } else {
        spmm_kernel<float><<<blocks, 256, 0, stream>>>(
            vals, rows, cols, mask, W, bias, row_ptr, out, nnz, n_nodes);
    }
}

// Round 4
// 165.879 us; speedup vs baseline: 2.3552x; 1.0791x over previous
//
#include <hip/hip_runtime.h>
#include <hip/hip_fp16.h>

#define ODIM 128
#define INV_KEEP 1.1111112f   // float(1.0/0.9)

// ---------- Fused prep kernel ----------
// Blocks [0, cvt_blocks): convert f32 W -> f16 into workspace.
// Blocks [cvt_blocks, ...): per-nnz: build vm[i] = mask ? val/keep : 0, and
// scatter CSR row_ptr from sorted rows[] (row_ptr[r] = first i with rows[i] >= r).
__global__ void prep_kernel(const float* __restrict__ w, __half* __restrict__ wh,
                            int w_elems,
                            const int*   __restrict__ rows,
                            const float* __restrict__ vals,
                            const int*   __restrict__ mask,
                            int*   __restrict__ row_ptr,
                            float* __restrict__ vm,
                            int nnz, int n_nodes, int cvt_blocks) {
    if ((int)blockIdx.x < cvt_blocks) {
        int i4 = (blockIdx.x * 256 + threadIdx.x) * 4;
        if (i4 + 3 < w_elems) {
            float4 f = *(const float4*)(w + i4);
            *(__half2*)(wh + i4)     = __floats2half2_rn(f.x, f.y);
            *(__half2*)(wh + i4 + 2) = __floats2half2_rn(f.z, f.w);
        } else {
            for (int k = i4; k < w_elems; ++k) wh[k] = __float2half(w[k]);
        }
    } else {
        int i = (blockIdx.x - cvt_blocks) * 256 + threadIdx.x;
        if (i >= nnz) return;
        if (vm) vm[i] = mask[i] ? vals[i] * INV_KEEP : 0.0f;
        if (row_ptr) {
            int r_cur  = rows[i];
            int r_prev = (i == 0) ? -1 : rows[i - 1];
            for (int r = r_prev + 1; r <= r_cur; ++r) row_ptr[r] = i;
            if (i == nnz - 1)
                for (int r = r_cur + 1; r <= n_nodes; ++r) row_ptr[r] = nnz;
        }
    }
}

// ---------- helpers: load a 2-wide W fragment as float2 ----------
__device__ __forceinline__ float2 load_w2(const __half* __restrict__ wh, int off) {
    __half2 h = *(const __half2*)(wh + off);
    return __half22float2(h);
}
__device__ __forceinline__ float2 load_w2(const float* __restrict__ wf, int off) {
    return *(const float2*)(wf + off);
}

// ---------- Main SpMM: one wave per output row ----------
// Lane owns output columns (2*lane, 2*lane+1). All per-nnz scalars are
// wave-uniform (SGPR) loads; W gathers are coalesced 256B wave loads with 8
// independent in flight. Rows are processed in PADDED batches of 8 with
// scalar predication (clamped index, v=0 for pads) -> zero serial remainder
// iterations, no branches on the vector path. Output stored non-temporally
// so the 51MB stream doesn't evict the hot W tile from L2.
template <typename WT, bool USE_VM>
__global__ void __launch_bounds__(256, 8)
spmm_kernel(const float* __restrict__ vals,
            const int*   __restrict__ rows,
            const int*   __restrict__ cols,
            const int*   __restrict__ mask,
            const float* __restrict__ vm,
            const WT*    __restrict__ wmat,
            const float* __restrict__ bias,
            const int*   __restrict__ row_ptr,   // may be null -> binary search
            float*       __restrict__ out,
            int nnz, int n_nodes) {
    const int wave = threadIdx.x >> 6;
    const int lane = threadIdx.x & 63;
    const int row  = blockIdx.x * 4 + wave;
    if (row >= n_nodes) return;
    const int cofs = 2 * lane;

    int i0, i1;
    if (row_ptr) {
        i0 = __builtin_amdgcn_readfirstlane(row_ptr[row]);
        i1 = __builtin_amdgcn_readfirstlane(row_ptr[row + 1]);
    } else {
        auto lb = [&](int target) {
            int lo = 0, hi = nnz;
            while (lo < hi) {
                int mid = (lo + hi) >> 1;
                if (rows[mid] < target) lo = mid + 1; else hi = mid;
            }
            return lo;
        };
        i0 = __builtin_amdgcn_readfirstlane(lb(row));
        i1 = __builtin_amdgcn_readfirstlane(lb(row + 1));
    }

    float2 acc = ((const float2*)bias)[lane];

    for (int i = i0; i < i1; i += 8) {
        int c[8];
        float v[8];
        float2 w[8];
        #pragma unroll
        for (int k = 0; k < 8; ++k) {
            int  idx = i + k;
            bool ok  = idx < i1;
            int  idc = ok ? idx : (i1 - 1);   // clamp: safe, cached line
            c[k] = cols[idc];
            float vv;
            if (USE_VM) {
                vv = vm[idc];
            } else {
                vv = mask[idc] ? vals[idc] * INV_KEEP : 0.0f;
            }
            v[k] = ok ? vv : 0.0f;
        }
        #pragma unroll
        for (int k = 0; k < 8; ++k) w[k] = load_w2(wmat, c[k] * ODIM + cofs);
        #pragma unroll
        for (int k = 0; k < 8; ++k) {
            acc.x = fmaf(v[k], w[k].x, acc.x);
            acc.y = fmaf(v[k], w[k].y, acc.y);
        }
    }

    union { float2 f2; unsigned long long u; } pk;
    pk.f2 = acc;
    __builtin_nontemporal_store(pk.u,
        (unsigned long long*)(out + (size_t)row * ODIM + cofs));
}

extern "C" void kernel_launch(void* const* d_in, const int* in_sizes, int n_in,
                              void* d_out, int out_size, void* d_ws, size_t ws_size,
                              hipStream_t stream) {
    const float* vals = (const float*)d_in[0];
    const int*   rows = (const int*)  d_in[1];
    const int*   cols = (const int*)  d_in[2];
    const int*   mask = (const int*)  d_in[3];
    const float* W    = (const float*)d_in[4];
    const float* bias = (const float*)d_in[5];
    float*       out  = (float*)d_out;

    const int nnz     = in_sizes[0];
    const int w_elems = in_sizes[4];             // INPUT_DIM * OUTPUT_DIM
    const int n_nodes = out_size / ODIM;

    // workspace layout: [W as f16 | row_ptr | vm], each 256B aligned
    const size_t wh_bytes = ((size_t)w_elems * sizeof(__half) + 255) & ~(size_t)255;
    const size_t rp_bytes = ((size_t)(n_nodes + 1) * sizeof(int) + 255) & ~(size_t)255;
    const size_t vm_bytes = (size_t)nnz * sizeof(float);

    __half* wh = nullptr;
    int* row_ptr = nullptr;
    float* vm = nullptr;
    if (ws_size >= wh_bytes + rp_bytes + vm_bytes) {
        wh      = (__half*)d_ws;
        row_ptr = (int*)((char*)d_ws + wh_bytes);
        vm      = (float*)((char*)d_ws + wh_bytes + rp_bytes);
    } else if (ws_size >= wh_bytes + rp_bytes) {
        wh      = (__half*)d_ws;
        row_ptr = (int*)((char*)d_ws + wh_bytes);
    } else if (ws_size >= rp_bytes) {
        row_ptr = (int*)d_ws;
    }

    const int cvt_blocks = wh ? (w_elems / 4 + 255) / 256 : 0;
    const int nz_blocks  = (row_ptr || vm) ? (nnz + 255) / 256 : 0;
    if (cvt_blocks + nz_blocks > 0)
        prep_kernel<<<cvt_blocks + nz_blocks, 256, 0, stream>>>(
            W, wh, w_elems, rows, vals, mask, row_ptr, vm, nnz, n_nodes, cvt_blocks);

    const int blocks = (n_nodes + 3) / 4;   // 4 rows (waves) per 256-thread block
    if (wh && vm) {
        spmm_kernel<__half, true><<<blocks, 256, 0, stream>>>(
            vals, rows, cols, mask, vm, wh, bias, row_ptr, out, nnz, n_nodes);
    } else if (wh) {
        spmm_kernel<__half, false><<<blocks, 256, 0, stream>>>(
            vals, rows, cols, mask, nullptr, wh, bias, row_ptr, out, nnz, n_nodes);
    } else {
        spmm_kernel<float, false><<<blocks, 256, 0, stream>>>(
            vals, rows, cols, mask, nullptr, W, bias, row_ptr, out, nnz, n_nodes);
    }
}

// Round 5
// 151.874 us; speedup vs baseline: 2.5724x; 1.0922x over previous
//
#include <hip/hip_runtime.h>
#include <hip/hip_fp16.h>

#define ODIM 128
#define INV_KEEP 1.1111112f   // float(1.0/0.9)

// ---------- Fused prep kernel ----------
// Blocks [0, cvt_blocks): convert f32 W -> f16 into workspace (4 elems/thread).
// Blocks [cvt_blocks, ...): build CSR row_ptr from sorted rows[] by scatter
// (4 nnz per thread): row_ptr[r] = first i with rows[i] >= r.
__global__ void prep_kernel(const float* __restrict__ w, __half* __restrict__ wh,
                            int w_elems,
                            const int* __restrict__ rows, int* __restrict__ row_ptr,
                            int nnz, int n_nodes, int cvt_blocks) {
    if ((int)blockIdx.x < cvt_blocks) {
        int i4 = (blockIdx.x * 256 + threadIdx.x) * 4;
        if (i4 + 3 < w_elems) {
            float4 f = *(const float4*)(w + i4);
            *(__half2*)(wh + i4)     = __floats2half2_rn(f.x, f.y);
            *(__half2*)(wh + i4 + 2) = __floats2half2_rn(f.z, f.w);
        } else {
            for (int k = i4; k < w_elems; ++k) wh[k] = __float2half(w[k]);
        }
    } else {
        int i4 = ((blockIdx.x - cvt_blocks) * 256 + threadIdx.x) * 4;
        if (i4 >= nnz) return;
        int rprev = (i4 == 0) ? -1 : rows[i4 - 1];
        #pragma unroll
        for (int k = 0; k < 4; ++k) {
            int i = i4 + k;
            if (i < nnz) {
                int rc = rows[i];
                for (int r = rprev + 1; r <= rc; ++r) row_ptr[r] = i;
                if (i == nnz - 1)
                    for (int r = rc + 1; r <= n_nodes; ++r) row_ptr[r] = nnz;
                rprev = rc;
            }
        }
    }
}

// ---------- helpers ----------
__device__ __forceinline__ float2 load_w2(const __half* __restrict__ wh, int off) {
    __half2 h = *(const __half2*)(wh + off);
    return __half22float2(h);
}
__device__ __forceinline__ float2 load_w2(const float* __restrict__ wf, int off) {
    return *(const float2*)(wf + off);
}
__device__ __forceinline__ float readlane_f(float x, int l) {
    return __uint_as_float(__builtin_amdgcn_readlane(__float_as_uint(x), l));
}

// ---------- Main SpMM: one wave per output row ----------
// Lane i cooperatively loads nnz i of the row's slice (coalesced); per-nnz
// scalars are then extracted with v_readlane (no scalar-memory chain at all).
// W gathers are coalesced 256B wave loads, 8 independent in flight. Padded
// batches of 8 via scalar predication; no branches on the vector path.
template <typename WT>
__global__ void __launch_bounds__(256, 8)
spmm_kernel(const float* __restrict__ vals,
            const int*   __restrict__ rows,
            const int*   __restrict__ cols,
            const int*   __restrict__ mask,
            const WT*    __restrict__ wmat,
            const float* __restrict__ bias,
            const int*   __restrict__ row_ptr,   // may be null -> binary search
            float*       __restrict__ out,
            int nnz, int n_nodes) {
    const int wave = threadIdx.x >> 6;
    const int lane = threadIdx.x & 63;
    const int row  = blockIdx.x * 4 + wave;
    if (row >= n_nodes) return;
    const int cofs = 2 * lane;

    int i0, i1;
    if (row_ptr) {
        i0 = __builtin_amdgcn_readfirstlane(row_ptr[row]);
        i1 = __builtin_amdgcn_readfirstlane(row_ptr[row + 1]);
    } else {
        auto lb = [&](int target) {
            int lo = 0, hi = nnz;
            while (lo < hi) {
                int mid = (lo + hi) >> 1;
                if (rows[mid] < target) lo = mid + 1; else hi = mid;
            }
            return lo;
        };
        i0 = __builtin_amdgcn_readfirstlane(lb(row));
        i1 = __builtin_amdgcn_readfirstlane(lb(row + 1));
    }

    float2 acc = ((const float2*)bias)[lane];

    // chunks of up to 64 nnz (one per lane); typical row fits in one chunk
    for (int base = i0; base < i1; base += 64) {
        const int rem = i1 - base;
        const int cnt = rem < 64 ? rem : 64;          // SGPR
        const int idx = base + lane;
        const int idc = idx < i1 ? idx : (i1 - 1);    // clamp (valid: base<i1)
        // one coalesced vector load per stream for the whole chunk
        const int   c_lane = cols[idc];
        const float va     = vals[idc];
        const int   ma     = mask[idc];
        const float v_lane = (idx < i1 && ma) ? va * INV_KEEP : 0.0f;

        for (int k0 = 0; k0 < cnt; k0 += 8) {
            float2 w[8];
            float  v[8];
            #pragma unroll
            for (int k = 0; k < 8; ++k) {
                const int kk = k0 + k;                        // SGPR, always <64
                const int   ck = __builtin_amdgcn_readlane(c_lane, kk);
                const float vk = readlane_f(v_lane, kk);
                v[k] = (kk < cnt) ? vk : 0.0f;                // scalar predicate
                w[k] = load_w2(wmat, ck * ODIM + cofs);       // pad: wasted, safe
            }
            #pragma unroll
            for (int k = 0; k < 8; ++k) {
                acc.x = fmaf(v[k], w[k].x, acc.x);
                acc.y = fmaf(v[k], w[k].y, acc.y);
            }
        }
    }

    union { float2 f2; unsigned long long u; } pk;
    pk.f2 = acc;
    __builtin_nontemporal_store(pk.u,
        (unsigned long long*)(out + (size_t)row * ODIM + cofs));
}

extern "C" void kernel_launch(void* const* d_in, const int* in_sizes, int n_in,
                              void* d_out, int out_size, void* d_ws, size_t ws_size,
                              hipStream_t stream) {
    const float* vals = (const float*)d_in[0];
    const int*   rows = (const int*)  d_in[1];
    const int*   cols = (const int*)  d_in[2];
    const int*   mask = (const int*)  d_in[3];
    const float* W    = (const float*)d_in[4];
    const float* bias = (const float*)d_in[5];
    float*       out  = (float*)d_out;

    const int nnz     = in_sizes[0];
    const int w_elems = in_sizes[4];             // INPUT_DIM * OUTPUT_DIM
    const int n_nodes = out_size / ODIM;

    // workspace layout: [W as f16 (256B aligned) | row_ptr (n_nodes+1 ints)]
    const size_t wh_bytes = ((size_t)w_elems * sizeof(__half) + 255) & ~(size_t)255;
    const size_t rp_bytes = (size_t)(n_nodes + 1) * sizeof(int);

    __half* wh = nullptr;
    int* row_ptr = nullptr;
    if (ws_size >= wh_bytes + rp_bytes) {
        wh = (__half*)d_ws;
        row_ptr = (int*)((char*)d_ws + wh_bytes);
    } else if (ws_size >= rp_bytes) {
        row_ptr = (int*)d_ws;
    }

    const int cvt_blocks = wh ? (w_elems / 4 + 255) / 256 : 0;
    const int rp_blocks  = row_ptr ? ((nnz + 3) / 4 + 255) / 256 : 0;
    if (cvt_blocks + rp_blocks > 0)
        prep_kernel<<<cvt_blocks + rp_blocks, 256, 0, stream>>>(
            W, wh, w_elems, rows, row_ptr, nnz, n_nodes, cvt_blocks);

    const int blocks = (n_nodes + 3) / 4;   // 4 rows (waves) per 256-thread block
    if (wh) {
        spmm_kernel<__half><<<blocks, 256, 0, stream>>>(
            vals, rows, cols, mask, wh, bias, row_ptr, out, nnz, n_nodes);
    } else {
        spmm_kernel<float><<<blocks, 256, 0, stream>>>(
            vals, rows, cols, mask, W, bias, row_ptr, out, nnz, n_nodes);
    }
}

// Round 6
// 146.367 us; speedup vs baseline: 2.6692x; 1.0376x over previous
//
#include <hip/hip_runtime.h>
#include <hip/hip_fp16.h>

#define ODIM 128
#define INV_KEEP 1.1111112f   // float(1.0/0.9)

// ---------- Fused prep kernel ----------
// Blocks [0, cvt_blocks): convert f32 W -> f16 into workspace (4 elems/thread).
// Blocks [cvt_blocks, ...): build CSR row_ptr from sorted rows[] by scatter
// (4 nnz per thread): row_ptr[r] = first i with rows[i] >= r.
__global__ void prep_kernel(const float* __restrict__ w, __half* __restrict__ wh,
                            int w_elems,
                            const int* __restrict__ rows, int* __restrict__ row_ptr,
                            int nnz, int n_nodes, int cvt_blocks) {
    if ((int)blockIdx.x < cvt_blocks) {
        int i4 = (blockIdx.x * 256 + threadIdx.x) * 4;
        if (i4 + 3 < w_elems) {
            float4 f = *(const float4*)(w + i4);
            *(__half2*)(wh + i4)     = __floats2half2_rn(f.x, f.y);
            *(__half2*)(wh + i4 + 2) = __floats2half2_rn(f.z, f.w);
        } else {
            for (int k = i4; k < w_elems; ++k) wh[k] = __float2half(w[k]);
        }
    } else {
        int i4 = ((blockIdx.x - cvt_blocks) * 256 + threadIdx.x) * 4;
        if (i4 >= nnz) return;
        int rprev = (i4 == 0) ? -1 : rows[i4 - 1];
        #pragma unroll
        for (int k = 0; k < 4; ++k) {
            int i = i4 + k;
            if (i < nnz) {
                int rc = rows[i];
                for (int r = rprev + 1; r <= rc; ++r) row_ptr[r] = i;
                if (i == nnz - 1)
                    for (int r = rc + 1; r <= n_nodes; ++r) row_ptr[r] = nnz;
                rprev = rc;
            }
        }
    }
}

// ---------- helpers ----------
__device__ __forceinline__ float readlane_f(float x, int l) {
    return __uint_as_float(__builtin_amdgcn_readlane(__float_as_uint(x), l));
}

// gather one W fragment: UNIFORM row pointer (SGPR, from readlane'd col) +
// loop-invariant lane offset -> global_load_dword v, v_laneoff, s[wp].
// FMA written as fpext(f16)->fma so LLVM can fuse into v_fma_mix_f32.
__device__ __forceinline__ void gather(const __half* __restrict__ wmat,
                                       unsigned ck, int lane, __half2& h) {
    const __half2* wp = (const __half2*)wmat + ((size_t)ck << 6);  // ck*256B
    h = wp[lane];
}
__device__ __forceinline__ void gather(const float* __restrict__ wmat,
                                       unsigned ck, int lane, float2& h) {
    const float2* wp = (const float2*)wmat + ((size_t)ck << 6);    // ck*512B
    h = wp[lane];
}
__device__ __forceinline__ void fma2(float v, const __half2& h, float2& acc) {
    acc.x = fmaf(v, __half2float(__low2half(h)),  acc.x);
    acc.y = fmaf(v, __half2float(__high2half(h)), acc.y);
}
__device__ __forceinline__ void fma2(float v, const float2& h, float2& acc) {
    acc.x = fmaf(v, h.x, acc.x);
    acc.y = fmaf(v, h.y, acc.y);
}

// ---------- Main SpMM: one wave per output row ----------
// Lane i cooperatively loads nnz i of the row's slice (coalesced); per-nnz
// scalars extracted with v_readlane (no scalar-memory chain). Gathers use a
// uniform SGPR row pointer + invariant lane offset (no per-nnz vector
// address math), 8 independent in flight. Padded batches of 8; no branches
// on the vector path.
template <typename WT, typename FRAG>
__global__ void __launch_bounds__(256, 8)
spmm_kernel(const float* __restrict__ vals,
            const int*   __restrict__ rows,
            const int*   __restrict__ cols,
            const int*   __restrict__ mask,
            const WT*    __restrict__ wmat,
            const float* __restrict__ bias,
            const int*   __restrict__ row_ptr,   // may be null -> binary search
            float*       __restrict__ out,
            int nnz, int n_nodes) {
    const int wave = threadIdx.x >> 6;
    const int lane = threadIdx.x & 63;
    const int row  = blockIdx.x * 4 + wave;
    if (row >= n_nodes) return;
    const int cofs = 2 * lane;

    int i0, i1;
    if (row_ptr) {
        i0 = __builtin_amdgcn_readfirstlane(row_ptr[row]);
        i1 = __builtin_amdgcn_readfirstlane(row_ptr[row + 1]);
    } else {
        auto lb = [&](int target) {
            int lo = 0, hi = nnz;
            while (lo < hi) {
                int mid = (lo + hi) >> 1;
                if (rows[mid] < target) lo = mid + 1; else hi = mid;
            }
            return lo;
        };
        i0 = __builtin_amdgcn_readfirstlane(lb(row));
        i1 = __builtin_amdgcn_readfirstlane(lb(row + 1));
    }

    float2 acc = ((const float2*)bias)[lane];

    // chunks of up to 64 nnz (one per lane); typical row fits in one chunk
    for (int base = i0; base < i1; base += 64) {
        const int rem = i1 - base;
        const int cnt = rem < 64 ? rem : 64;          // SGPR
        const int idx = base + lane;
        const int idc = idx < i1 ? idx : (i1 - 1);    // clamp (valid: base<i1)
        // one coalesced vector load per stream for the whole chunk
        const int   c_lane = cols[idc];
        const float va     = vals[idc];
        const int   ma     = mask[idc];
        const float v_lane = (idx < i1 && ma) ? va * INV_KEEP : 0.0f;

        for (int k0 = 0; k0 < cnt; k0 += 8) {
            FRAG  h[8];
            float v[8];
            #pragma unroll
            for (int k = 0; k < 8; ++k) {
                const int kk = k0 + k;                        // SGPR, always <64
                const unsigned ck = (unsigned)__builtin_amdgcn_readlane(c_lane, kk);
                const float    vk = readlane_f(v_lane, kk);
                v[k] = (kk < cnt) ? vk : 0.0f;                // scalar predicate
                gather(wmat, ck, lane, h[k]);                 // pad: wasted, safe
            }
            #pragma unroll
            for (int k = 0; k < 8; ++k) fma2(v[k], h[k], acc);
        }
    }

    union { float2 f2; unsigned long long u; } pk;
    pk.f2 = acc;
    __builtin_nontemporal_store(pk.u,
        (unsigned long long*)(out + (size_t)row * ODIM + cofs));
}

extern "C" void kernel_launch(void* const* d_in, const int* in_sizes, int n_in,
                              void* d_out, int out_size, void* d_ws, size_t ws_size,
                              hipStream_t stream) {
    const float* vals = (const float*)d_in[0];
    const int*   rows = (const int*)  d_in[1];
    const int*   cols = (const int*)  d_in[2];
    const int*   mask = (const int*)  d_in[3];
    const float* W    = (const float*)d_in[4];
    const float* bias = (const float*)d_in[5];
    float*       out  = (float*)d_out;

    const int nnz     = in_sizes[0];
    const int w_elems = in_sizes[4];             // INPUT_DIM * OUTPUT_DIM
    const int n_nodes = out_size / ODIM;

    // workspace layout: [W as f16 (256B aligned) | row_ptr (n_nodes+1 ints)]
    const size_t wh_bytes = ((size_t)w_elems * sizeof(__half) + 255) & ~(size_t)255;
    const size_t rp_bytes = (size_t)(n_nodes + 1) * sizeof(int);

    __half* wh = nullptr;
    int* row_ptr = nullptr;
    if (ws_size >= wh_bytes + rp_bytes) {
        wh = (__half*)d_ws;
        row_ptr = (int*)((char*)d_ws + wh_bytes);
    } else if (ws_size >= rp_bytes) {
        row_ptr = (int*)d_ws;
    }

    const int cvt_blocks = wh ? (w_elems / 4 + 255) / 256 : 0;
    const int rp_blocks  = row_ptr ? ((nnz + 3) / 4 + 255) / 256 : 0;
    if (cvt_blocks + rp_blocks > 0)
        prep_kernel<<<cvt_blocks + rp_blocks, 256, 0, stream>>>(
            W, wh, w_elems, rows, row_ptr, nnz, n_nodes, cvt_blocks);

    const int blocks = (n_nodes + 3) / 4;   // 4 rows (waves) per 256-thread block
    if (wh) {
        spmm_kernel<__half, __half2><<<blocks, 256, 0, stream>>>(
            vals, rows, cols, mask, wh, bias, row_ptr, out, nnz, n_nodes);
    } else {
        spmm_kernel<float, float2><<<blocks, 256, 0, stream>>>(
            vals, rows, cols, mask, W, bias, row_ptr, out, nnz, n_nodes);
    }
}